// Round 7
// baseline (234.024 us; speedup 1.0000x reference)
//
#include <hip/hip_runtime.h>
#include <math.h>

// B=16, C=512, HW=1024.  Chain (per batch):
//   X  (C x HW)  = n1 @ W_c^T
//   E  (HW x HW) = X^T @ n2
//   A  = row-softmax(E)
//   out(C x HW)  = n2 @ A
//
// Round 14: m97-style DMA staging. All reg-round-trip staging replaced by
// __builtin_amdgcn_global_load_lds (16B): LDS dest lane-linear, global source
// PRE-SWIZZLED (lane fetches granule ls^((r>>1)&3)) so fragment reads keep
// the verified-0-conflict XOR pattern (swz16). One __syncthreads per K-step
// (its vmcnt drain is the only stall; overlapped by co-resident blocks).
// gemm3's exp fusion moved to a standalone at_scale pass (exact same math),
// so all three GEMMs share one clean DMA core (256 thr, 4 waves, 128x128,
// BK=32, 16 MFMA / 8 ds_read_b128 per wave-step).
//
// Workspace (96 MiB, lifetime-aliased):
//   [0,16M):   n2t  f16 (prep -> gemm2)     } At f16 [0,32M) after gemm2
//   [16,32M):  Xt   f16 (gemm1 -> gemm2)    }   (at_scale -> gemm3)
//   [32,34M):  Wf   f16 (prep -> gemm1; overlaid by Et)
//   [32,64M):  Et   f16 (gemm2 -> at_scale)
//   [64,80M):  n1f  f16 (prep -> gemm1); Pm/Ps/Sc overlay afterwards
//   [80,96M):  n2f  f16 (prep -> gemm3)

typedef _Float16 f16;
typedef _Float16 f16x8 __attribute__((ext_vector_type(8)));
typedef _Float16 f16x4 __attribute__((ext_vector_type(4)));
typedef float f32x4 __attribute__((ext_vector_type(4)));

#define L2E 1.442695040888963f

#define DMA16(g, l)                                                             \
    __builtin_amdgcn_global_load_lds(                                           \
        (const __attribute__((address_space(1))) void*)(g),                     \
        (__attribute__((address_space(3))) void*)(l), 16, 0, 0)

// ---------------------------------------------------------------------------
// Fused pre-pass. blockIdx.x:
//   [0,4096):    n1 -> n1f     [4096,4608): Wc -> Wf
//   [4608,6656): n2 -> n2f (natural) + n2t (transposed)
__global__ __launch_bounds__(256) void prep(const float* __restrict__ n1,
                                            const float* __restrict__ Wc,
                                            const float* __restrict__ n2,
                                            f16* __restrict__ n1f, f16* __restrict__ Wf,
                                            f16* __restrict__ n2f, f16* __restrict__ n2t) {
    const int bid = blockIdx.x, tid = threadIdx.x;
    if (bid < 4608) {
        const float* s = (bid < 4096) ? n1 : Wc;
        f16* d = (bid < 4096) ? n1f : Wf;
        const size_t i = ((size_t)(bid < 4096 ? bid : bid - 4096) * 256 + tid) * 8;
        f32x4 a = *(const f32x4*)(s + i);
        f32x4 b = *(const f32x4*)(s + i + 4);
        f16x8 o;
        o[0] = (f16)a[0]; o[1] = (f16)a[1]; o[2] = (f16)a[2]; o[3] = (f16)a[3];
        o[4] = (f16)b[0]; o[5] = (f16)b[1]; o[6] = (f16)b[2]; o[7] = (f16)b[3];
        *(f16x8*)(d + i) = o;
        return;
    }
    const int id = bid - 4608;
    const int b = id >> 7;
    const int ry = (id & 127) >> 4;
    const int cx = id & 15;
    const float* S = n2 + (size_t)b * 512 * 1024;
    f16* Dn = n2f + (size_t)b * 512 * 1024;
    f16* Dt = n2t + (size_t)b * 1024 * 512;
    __shared__ f16 Ts[64 * 72];
    const int r0 = ry * 64, c0 = cx * 64;
    const int rr = tid >> 3, cc8 = (tid & 7) * 8;
#pragma unroll
    for (int h = 0; h < 2; ++h) {
        const int row = r0 + rr + 32 * h;
        const float* s = S + (size_t)row * 1024 + c0 + cc8;
        f32x4 a = *(const f32x4*)s, bq = *(const f32x4*)(s + 4);
        f16x8 o;
        o[0] = (f16)a[0]; o[1] = (f16)a[1]; o[2] = (f16)a[2]; o[3] = (f16)a[3];
        o[4] = (f16)bq[0]; o[5] = (f16)bq[1]; o[6] = (f16)bq[2]; o[7] = (f16)bq[3];
        *(f16x8*)&Ts[(rr + 32 * h) * 72 + cc8] = o;
        *(f16x8*)(Dn + (size_t)row * 1024 + c0 + cc8) = o;
    }
    __syncthreads();
    const int j = tid >> 2, k16 = (tid & 3) * 16;
    f16* d = Dt + (size_t)(c0 + j) * 512 + r0 + k16;
    f16x8 o0, o1;
#pragma unroll
    for (int i = 0; i < 8; ++i) {
        o0[i] = Ts[(k16 + i) * 72 + j];
        o1[i] = Ts[(k16 + 8 + i) * 72 + j];
    }
    *(f16x8*)d = o0;
    *(f16x8*)(d + 8) = o1;
}

// ---------------------------------------------------------------------------
// stats_combine: per (b,o) fold 16 partials (log2 domain) ->
//   Sc[b][o] = log2(sum_h e^{E[o][h]}).
__global__ __launch_bounds__(256) void stats_combine(const float* __restrict__ Pm,
                                                     const float* __restrict__ Ps,
                                                     float* __restrict__ Sc) {
    const int g = blockIdx.x * 256 + threadIdx.x;  // 16 * 1024
    const int b = g >> 10, o = g & 1023;
    const int mt = o >> 7, ml = o & 127;
    const float* pm = Pm + ((size_t)(b * 8 + mt) * 16) * 128 + ml;
    const float* ps = Ps + ((size_t)(b * 8 + mt) * 16) * 128 + ml;
    float M = -3.0e38f;
#pragma unroll
    for (int p = 0; p < 16; ++p) M = fmaxf(M, pm[p * 128]);
    float S = 0.f;
#pragma unroll
    for (int p = 0; p < 16; ++p) S += ps[p * 128] * exp2f(pm[p * 128] - M);
    Sc[g] = M + __log2f(S);
}

// ---------------------------------------------------------------------------
// exp-scale: At = exp2(Et*log2e - Sc)
__device__ __forceinline__ f16x8 expb(f16x8 b, f32x4 cl, f32x4 ch) {
    f16x8 t;
#pragma unroll
    for (int i = 0; i < 4; ++i) t[i] = (f16)exp2f(fmaf((float)b[i], L2E, -cl[i]));
#pragma unroll
    for (int i = 0; i < 4; ++i) t[4 + i] = (f16)exp2f(fmaf((float)b[4 + i], L2E, -ch[i]));
    return t;
}

// at_scale: At[b][j][o] = exp2(Et[b][j][o]*L2E - Sc[b][o]). 2 rows per block.
__global__ __launch_bounds__(256) void at_scale(const f16* __restrict__ Et,
                                                const float* __restrict__ Sc,
                                                f16* __restrict__ At) {
    const int gid = blockIdx.x;            // 0..8191
    const int b = gid >> 9;
    const int row = (gid & 511) * 2 + (threadIdx.x >> 7);
    const int ch = threadIdx.x & 127;      // 8-elem chunk of o
    const size_t base = ((size_t)b << 20) + ((size_t)row << 10) + ch * 8;
    const float* sc = Sc + (b << 10) + ch * 8;
    f16x8 v = *(const f16x8*)(Et + base);
    f32x4 c0 = *(const f32x4*)sc, c1 = *(const f32x4*)(sc + 4);
    *(f16x8*)(At + base) = expb(v, c0, c1);
}

// ---------------------------------------------------------------------------
// DMA K-loop core. BM=BN=128, BK=32, 256 threads, 4 waves (2m x 2n), wave
// tile 64x64: 16 MFMA per 8 ds_read_b128 per step.
// LDS: A bufs @0/8192, B bufs @16384/24576 (32 KB). Rows 64 B, lane-linear
// DMA dest; global source pre-swizzled (granule ls ^ ((r>>1)&3)) so reads
// use swz16 = (quad ^ ((col>>1)&3))*16 -> 0 bank conflicts (verified R13).
// One __syncthreads per step (drains DMA for the next buffer).
template <int NS>
__device__ __forceinline__ void gemm_dma(const char* gA, const char* gB,
                                         const int ldK, char* SM, int tid,
                                         int wm, int wn, int col, int swz16,
                                         f32x4 (&acc)[4][4]) {
    const int r = tid >> 2, ls = tid & 3;
    const int x = (r >> 1) & 3;
    const char* sA0 = gA + (size_t)r * ldK + (ls ^ x) * 16;
    const char* sA1 = sA0 + (size_t)64 * ldK;
    const char* sB0 = gB + (size_t)r * ldK + (ls ^ x) * 16;
    const char* sB1 = sB0 + (size_t)64 * ldK;
    const int wave = tid >> 6;
    char* dA = SM + wave * 1024;
    char* dB = SM + 16384 + wave * 1024;
    DMA16(sA0, dA); DMA16(sA1, dA + 4096);
    DMA16(sB0, dB); DMA16(sB1, dB + 4096);
    __syncthreads();
#pragma unroll
    for (int kb = 0; kb < NS; ++kb) {
        if (kb + 1 < NS) {
            const int nb = ((kb + 1) & 1) * 8192;
            const int o = (kb + 1) * 64;
            DMA16(sA0 + o, dA + nb); DMA16(sA1 + o, dA + nb + 4096);
            DMA16(sB0 + o, dB + nb); DMA16(sB1 + o, dB + nb + 4096);
        }
        const char* Ac = SM + (kb & 1) * 8192;
        const char* Bc = SM + 16384 + (kb & 1) * 8192;
        f16x8 fa[4], fb[4];
#pragma unroll
        for (int u = 0; u < 4; ++u)
            fa[u] = *(const f16x8*)(Ac + (wm + u * 16 + col) * 64 + swz16);
#pragma unroll
        for (int v = 0; v < 4; ++v)
            fb[v] = *(const f16x8*)(Bc + (wn + v * 16 + col) * 64 + swz16);
#pragma unroll
        for (int u = 0; u < 4; ++u)
#pragma unroll
            for (int v = 0; v < 4; ++v)
                acc[u][v] = __builtin_amdgcn_mfma_f32_16x16x32_f16(fa[u], fb[v],
                                                                   acc[u][v], 0, 0, 0);
        __syncthreads();
    }
}

// Transposed f16 epilogue: single pass through Tt[128][136]; each wave writes
// its 64x64 quadrant, then 256 threads copy 128 coalesced rows of 128.
__device__ __forceinline__ void epilogue_tr128(f32x4 (&acc)[4][4], char* SM,
                                               f16* dst0, int dstRow, int m0,
                                               int n0, int tid) {
    const int lane = tid & 63, wave = tid >> 6;
    const int col = lane & 15, quad = lane >> 4;
    const int wm = ((wave >> 1) & 1) * 64, wn = (wave & 1) * 64;
    f16* Tt = (f16*)SM;   // prior loop ended with __syncthreads -> SM free
#pragma unroll
    for (int u = 0; u < 4; ++u)
#pragma unroll
        for (int v = 0; v < 4; ++v) {
            f16x4 p;
#pragma unroll
            for (int r = 0; r < 4; ++r) p[r] = (f16)acc[u][v][r];
            *(f16x4*)&Tt[(wn + v * 16 + col) * 136 + wm + u * 16 + quad * 4] = p;
        }
    __syncthreads();
    const int j = tid >> 1, seg = (tid & 1) * 64;
    f16* dst = dst0 + (size_t)(n0 + j) * dstRow + m0 + seg;
#pragma unroll
    for (int c8 = 0; c8 < 64; c8 += 8)
        *(f16x8*)(dst + c8) = *(const f16x8*)&Tt[j * 136 + seg + c8];
}

// ---------------------------------------------------------------------------
// GEMM1: Xt[b][o][c] = (n1f[b] @ Wf^T)^T.  M=512, N=1024, K=1024. 512 blocks.
__global__ __launch_bounds__(256) void gemm1_nt_xt(const f16* __restrict__ A,
                                                   const f16* __restrict__ Bw,
                                                   f16* __restrict__ Xt) {
    const int id = blockIdx.x;
    const int xcd = id & 7, loc = id >> 3;         // loc 0..63
    const int b = xcd * 2 + (loc >> 5);
    const int m0 = ((loc >> 3) & 3) * 128;
    const int n0 = (loc & 7) * 128;
    __shared__ __attribute__((aligned(16))) char SM[34816];
    const int tid = threadIdx.x, lane = tid & 63, wave = tid >> 6;
    const int col = lane & 15, quad = lane >> 4;
    const int wm = ((wave >> 1) & 1) * 64, wn = (wave & 1) * 64;
    const int swz16 = (quad ^ ((col >> 1) & 3)) * 16;
    const char* gA = (const char*)(A + (size_t)b * 512 * 1024) + (size_t)m0 * 2048;
    const char* gB = (const char*)(Bw) + (size_t)n0 * 2048;
    f32x4 acc[4][4] = {};
    gemm_dma<32>(gA, gB, 2048, SM, tid, wm, wn, col, swz16, acc);
    epilogue_tr128(acc, SM, Xt + (size_t)b * 1024 * 512, 512, m0, n0, tid);
}

// ---------------------------------------------------------------------------
// GEMM2: Et[b][h][o] (f16) = (Xt[b] @ n2t[b]^T)^T.  M=1024, N=1024, K=512.
// 1024 blocks. Epilogue also emits per-block column (per-o) softmax partials
// from the f16-ROUNDED acc values (bit-consistent with stored Et).
__global__ __launch_bounds__(256) void gemm2_nt_et(const f16* __restrict__ A,
                                                   const f16* __restrict__ B,
                                                   f16* __restrict__ Et,
                                                   float* __restrict__ Pm,
                                                   float* __restrict__ Ps) {
    const int id = blockIdx.x;
    const int xcd = id & 7, loc = id >> 3;         // loc 0..127
    const int b = xcd * 2 + (loc >> 6);
    const int m0 = ((loc >> 3) & 7) * 128;
    const int n0 = (loc & 7) * 128;
    __shared__ __attribute__((aligned(16))) char SM[34816];
    const int tid = threadIdx.x, lane = tid & 63, wave = tid >> 6;
    const int col = lane & 15, quad = lane >> 4;
    const int wm = ((wave >> 1) & 1) * 64, wn = (wave & 1) * 64;
    const int swz16 = (quad ^ ((col >> 1) & 3)) * 16;
    const char* gA = (const char*)(A + (size_t)b * 1024 * 512) + (size_t)m0 * 1024;
    const char* gB = (const char*)(B + (size_t)b * 1024 * 512) + (size_t)n0 * 1024;
    f32x4 acc[4][4] = {};
    gemm_dma<16>(gA, gB, 1024, SM, tid, wm, wn, col, swz16, acc);

    // ---- fused column-softmax partials (log2 domain), registers + shfl only.
    {
        float pm[16], ps[16];
#pragma unroll
        for (int u = 0; u < 4; ++u)
#pragma unroll
            for (int r = 0; r < 4; ++r) {
                float w0 = (float)(f16)acc[u][0][r] * L2E;
                float w1 = (float)(f16)acc[u][1][r] * L2E;
                float w2 = (float)(f16)acc[u][2][r] * L2E;
                float w3 = (float)(f16)acc[u][3][r] * L2E;
                float m2 = fmaxf(fmaxf(w0, w1), fmaxf(w2, w3));
                float s = exp2f(w0 - m2) + exp2f(w1 - m2) +
                          exp2f(w2 - m2) + exp2f(w3 - m2);
                pm[u * 4 + r] = m2;
                ps[u * 4 + r] = s;
            }
#pragma unroll
        for (int d = 1; d < 16; d <<= 1)
#pragma unroll
            for (int i = 0; i < 16; ++i) {
                float om = __shfl_xor(pm[i], d, 64);
                float os = __shfl_xor(ps[i], d, 64);
                float nm = fmaxf(pm[i], om);
                ps[i] = ps[i] * exp2f(pm[i] - nm) + os * exp2f(om - nm);
                pm[i] = nm;
            }
        if (col == 0) {
            const int part = ((b * 8 + (m0 >> 7)) * 8 + (n0 >> 7)) * 2 + (wave & 1);
            float* bm = Pm + (size_t)part * 128;
            float* bs = Ps + (size_t)part * 128;
#pragma unroll
            for (int i = 0; i < 16; ++i) {
                const int ml = wm + (i >> 2) * 16 + quad * 4 + (i & 3);
                bm[ml] = pm[i];
                bs[ml] = ps[i];
            }
        }
    }

    epilogue_tr128(acc, SM, Et + (size_t)b * 1024 * 1024, 1024, m0, n0, tid);
}

// ---------------------------------------------------------------------------
// GEMM3: out[b][c][j] (f32) = n2f[b] @ At[b]^T.  M=512, N=1024, K=1024.
// 512 blocks. Clean DMA GEMM (exp already applied by at_scale).
__global__ __launch_bounds__(256) void gemm3_nt_out(const f16* __restrict__ A,
                                                    const f16* __restrict__ At,
                                                    float* __restrict__ C) {
    const int id = blockIdx.x;
    const int xcd = id & 7, loc = id >> 3;         // loc 0..63
    const int b = xcd * 2 + (loc >> 5);
    const int m0 = ((loc >> 3) & 3) * 128;
    const int n0 = (loc & 7) * 128;
    C += (size_t)b * 512 * 1024;
    __shared__ __attribute__((aligned(16))) char SM[32768];
    const int tid = threadIdx.x, lane = tid & 63, wave = tid >> 6;
    const int col = lane & 15, quad = lane >> 4;
    const int wm = ((wave >> 1) & 1) * 64, wn = (wave & 1) * 64;
    const int swz16 = (quad ^ ((col >> 1) & 3)) * 16;
    const char* gA = (const char*)(A + (size_t)b * 512 * 1024) + (size_t)m0 * 2048;
    const char* gB = (const char*)(At + (size_t)b * 1024 * 1024) + (size_t)n0 * 2048;
    f32x4 acc[4][4] = {};
    gemm_dma<32>(gA, gB, 2048, SM, tid, wm, wn, col, swz16, acc);

#pragma unroll
    for (int u = 0; u < 4; ++u)
#pragma unroll
        for (int v = 0; v < 4; ++v)
#pragma unroll
            for (int r = 0; r < 4; ++r)
                C[(size_t)(m0 + wm + u * 16 + quad * 4 + r) * 1024 + n0 + wn + v * 16 + col] =
                    acc[u][v][r];
}

// ---------------------------------------------------------------------------
extern "C" void kernel_launch(void* const* d_in, const int* in_sizes, int n_in,
                              void* d_out, int out_size, void* d_ws, size_t ws_size,
                              hipStream_t stream) {
    const float* n1 = (const float*)d_in[0];
    const float* n2 = (const float*)d_in[1];
    const float* Wc = (const float*)d_in[2];
    float* out = (float*)d_out;
    char* ws = (char*)d_ws;

    f16* n2t = (f16*)(ws);                   // [0,16M)   prep -> gemm2
    f16* Xt  = (f16*)(ws + (16u << 20));     // [16,32M)  gemm1 -> gemm2
    f16* At  = (f16*)(ws);                   // [0,32M)   at_scale -> gemm3
    f16* Wf  = (f16*)(ws + (32u << 20));     // [32,34M)  prep -> gemm1 (dead before Et)
    f16* Et  = (f16*)(ws + (32u << 20));     // [32,64M)  gemm2 -> at_scale
    f16* n1f = (f16*)(ws + (64u << 20));     // [64,80M)  prep -> gemm1 (dead after)
    f16* n2f = (f16*)(ws + (80u << 20));     // [80,96M)  prep -> gemm3
    float* Pm = (float*)(ws + (64u << 20));            // 1 MiB, over dead n1f
    float* Ps = (float*)(ws + (65u << 20));            // 1 MiB
    float* Sc = (float*)(ws + (66u << 20));            // 64 KiB (log2 units)

    prep<<<6656, dim3(256), 0, stream>>>(n1, Wc, n2, n1f, Wf, n2f, n2t);
    gemm1_nt_xt<<<512, dim3(256), 0, stream>>>(n1f, Wf, Xt);
    gemm2_nt_et<<<1024, dim3(256), 0, stream>>>(Xt, n2t, Et, Pm, Ps);
    stats_combine<<<64, dim3(256), 0, stream>>>(Pm, Ps, Sc);
    at_scale<<<8192, dim3(256), 0, stream>>>(Et, Sc, At);
    gemm3_nt_out<<<512, dim3(256), 0, stream>>>(n2f, At, out);
}

// Round 8
// 216.524 us; speedup vs baseline: 1.0808x; 1.0808x over previous
//
#include <hip/hip_runtime.h>
#include <math.h>

// B=16, C=512, HW=1024.  Chain (per batch):
//   X  (C x HW)  = n1 @ W_c^T
//   E  (HW x HW) = X^T @ n2
//   A  = row-softmax(E)
//   out(C x HW)  = n2 @ A
//
// Round 15: compose the measured-best pieces.
//  - GEMM core = round-11/R4 verbatim (best measured: all gemms <=40us):
//    512 threads, BM=256 BN=128 BK=32, 8 waves (4m x 2n), 64x64 wave tiles
//    (16 MFMA / 8 ds_read_b128), both-sides XOR swizzle (0 conflicts,
//    verified), depth-2 reg prefetch, exp fused in gemm3 B-staging.
//  - stats_partial pass DELETED: gemm2's epilogue computes column-softmax
//    partials from the f16-ROUNDED acc (bit-consistent with stored Et --
//    the R13-verified numerics), via in-thread v-reduce + 4-step shfl_xor
//    col-reduce. 16 partials per (b,o); stats_combine folds them.
//  - Pipeline: prep -> gemm1 -> gemm2(+stats) -> stats_combine -> gemm3.
//
// Workspace (96 MiB, lifetime-aliased):
//   [0,16M):   n2t  f16 (prep -> gemm2)
//   [16,32M):  Xt   f16 (gemm1 -> gemm2)
//   [32,34M):  Wf   f16 (prep -> gemm1; overlaid by Et)
//   [32,64M):  Et   f16 (gemm2 -> gemm3)
//   [64,80M):  n1f  f16 (prep -> gemm1); Pm/Ps/Sc overlay afterwards
//   [80,96M):  n2f  f16 (prep -> gemm3)

typedef _Float16 f16;
typedef _Float16 f16x8 __attribute__((ext_vector_type(8)));
typedef _Float16 f16x4 __attribute__((ext_vector_type(4)));
typedef float f32x4 __attribute__((ext_vector_type(4)));

#define L2E 1.442695040888963f

// Barrier with LDS-drain only (no vmcnt drain): prefetch survives it.
#define WG_BARRIER() asm volatile("s_waitcnt lgkmcnt(0)\ns_barrier" ::: "memory")

// ---------------------------------------------------------------------------
// Fused pre-pass. blockIdx.x:
//   [0,4096):    n1 -> n1f     [4096,4608): Wc -> Wf
//   [4608,6656): n2 -> n2f (natural) + n2t (transposed)
__global__ __launch_bounds__(256) void prep(const float* __restrict__ n1,
                                            const float* __restrict__ Wc,
                                            const float* __restrict__ n2,
                                            f16* __restrict__ n1f, f16* __restrict__ Wf,
                                            f16* __restrict__ n2f, f16* __restrict__ n2t) {
    const int bid = blockIdx.x, tid = threadIdx.x;
    if (bid < 4608) {
        const float* s = (bid < 4096) ? n1 : Wc;
        f16* d = (bid < 4096) ? n1f : Wf;
        const size_t i = ((size_t)(bid < 4096 ? bid : bid - 4096) * 256 + tid) * 8;
        f32x4 a = *(const f32x4*)(s + i);
        f32x4 b = *(const f32x4*)(s + i + 4);
        f16x8 o;
        o[0] = (f16)a[0]; o[1] = (f16)a[1]; o[2] = (f16)a[2]; o[3] = (f16)a[3];
        o[4] = (f16)b[0]; o[5] = (f16)b[1]; o[6] = (f16)b[2]; o[7] = (f16)b[3];
        *(f16x8*)(d + i) = o;
        return;
    }
    const int id = bid - 4608;
    const int b = id >> 7;
    const int ry = (id & 127) >> 4;
    const int cx = id & 15;
    const float* S = n2 + (size_t)b * 512 * 1024;
    f16* Dn = n2f + (size_t)b * 512 * 1024;
    f16* Dt = n2t + (size_t)b * 1024 * 512;
    __shared__ f16 Ts[64 * 72];
    const int r0 = ry * 64, c0 = cx * 64;
    const int rr = tid >> 3, cc8 = (tid & 7) * 8;
#pragma unroll
    for (int h = 0; h < 2; ++h) {
        const int row = r0 + rr + 32 * h;
        const float* s = S + (size_t)row * 1024 + c0 + cc8;
        f32x4 a = *(const f32x4*)s, bq = *(const f32x4*)(s + 4);
        f16x8 o;
        o[0] = (f16)a[0]; o[1] = (f16)a[1]; o[2] = (f16)a[2]; o[3] = (f16)a[3];
        o[4] = (f16)bq[0]; o[5] = (f16)bq[1]; o[6] = (f16)bq[2]; o[7] = (f16)bq[3];
        *(f16x8*)&Ts[(rr + 32 * h) * 72 + cc8] = o;
        *(f16x8*)(Dn + (size_t)row * 1024 + c0 + cc8) = o;
    }
    __syncthreads();
    const int j = tid >> 2, k16 = (tid & 3) * 16;
    f16* d = Dt + (size_t)(c0 + j) * 512 + r0 + k16;
    f16x8 o0, o1;
#pragma unroll
    for (int i = 0; i < 8; ++i) {
        o0[i] = Ts[(k16 + i) * 72 + j];
        o1[i] = Ts[(k16 + 8 + i) * 72 + j];
    }
    *(f16x8*)d = o0;
    *(f16x8*)(d + 8) = o1;
}

// ---------------------------------------------------------------------------
// stats_combine: per (b,o) fold 16 partials (log2 domain) ->
//   Sc[b][o] = log2(sum_h e^{E[o][h]}), in log2 units.
// Partial layout: Pm[((b*4 + mt)*16 + p)*256 + ml], p = nt*2 + nhalf,
// mt = o>>8, ml = o&255.
__global__ __launch_bounds__(256) void stats_combine(const float* __restrict__ Pm,
                                                     const float* __restrict__ Ps,
                                                     float* __restrict__ Sc) {
    const int g = blockIdx.x * 256 + threadIdx.x;  // 16 * 1024
    const int b = g >> 10, o = g & 1023;
    const int mt = o >> 8, ml = o & 255;
    const float* pm = Pm + ((size_t)(b * 4 + mt) * 16) * 256 + ml;
    const float* ps = Ps + ((size_t)(b * 4 + mt) * 16) * 256 + ml;
    float M = -3.0e38f;
#pragma unroll
    for (int p = 0; p < 16; ++p) M = fmaxf(M, pm[p * 256]);
    float S = 0.f;
#pragma unroll
    for (int p = 0; p < 16; ++p) S += ps[p * 256] * exp2f(pm[p * 256] - M);
    Sc[g] = M + __log2f(S);
}

// ---------------------------------------------------------------------------
// exp-scale of a staged B vector: At = exp2(Et*log2e - Sc)
__device__ __forceinline__ f16x8 expb(f16x8 b, f32x4 cl, f32x4 ch) {
    f16x8 t;
#pragma unroll
    for (int i = 0; i < 4; ++i) t[i] = (f16)exp2f(fmaf((float)b[i], L2E, -cl[i]));
#pragma unroll
    for (int i = 0; i < 4; ++i) t[4 + i] = (f16)exp2f(fmaf((float)b[4 + i], L2E, -ch[i]));
    return t;
}

// ---------------------------------------------------------------------------
// Shared K-loop core (R4 verbatim). BM=256, BN=128, BK=32, 512 threads,
// 8 waves (4m x 2n), wave tile 64x64: fa[4] x fb[4] -> 16 MFMA per
// 8 ds_read_b128. LDS: A0 @0 (16K), A1 @16384, B0 @32768 (8K), B1 @40960.
// Row = 64 B. Swizzle: 16B slot s of row r lives at s ^ ((r>>1)&3);
// applied on both stage-write (sOff) and fragment-read (swz16).
// Depth-2 global->reg prefetch.
template <int NS, bool EXPB>
__device__ __forceinline__ void gemm_core(const char* gA0, const char* gA1,
                                          const char* gB, const float* gSp,
                                          char* SM, int sOff, int wm, int wn,
                                          int col, int swz16, f32x4 (&acc)[4][4]) {
    f16x8 a00 = *(const f16x8*)gA0, a01 = *(const f16x8*)gA1;
    f16x8 b0 = *(const f16x8*)gB;
    f32x4 c00, c01, c10, c11;
    if (EXPB) { c00 = *(const f32x4*)gSp; c01 = *(const f32x4*)(gSp + 4); }
    {
        char* dA = SM + sOff;
        *(f16x8*)dA = a00;
        *(f16x8*)(dA + 8192) = a01;
        char* dB = SM + 32768 + sOff;
        *(f16x8*)dB = EXPB ? expb(b0, c00, c01) : b0;
    }
    f16x8 a10 = *(const f16x8*)(gA0 + 64), a11 = *(const f16x8*)(gA1 + 64);
    f16x8 b1 = *(const f16x8*)(gB + 64);
    if (EXPB) { c10 = *(const f32x4*)(gSp + 32); c11 = *(const f32x4*)(gSp + 36); }
    a00 = *(const f16x8*)(gA0 + 128); a01 = *(const f16x8*)(gA1 + 128);
    b0 = *(const f16x8*)(gB + 128);
    if (EXPB) { c00 = *(const f32x4*)(gSp + 64); c01 = *(const f32x4*)(gSp + 68); }
    WG_BARRIER();
#pragma unroll
    for (int kb = 0; kb < NS; ++kb) {
        const char* Ac = SM + (kb & 1) * 16384;
        const char* Bc = SM + 32768 + (kb & 1) * 8192;
        f16x8 fa[4], fb[4];
#pragma unroll
        for (int u = 0; u < 4; ++u)
            fa[u] = *(const f16x8*)(Ac + (wm + u * 16 + col) * 64 + swz16);
#pragma unroll
        for (int v = 0; v < 4; ++v)
            fb[v] = *(const f16x8*)(Bc + (wn + v * 16 + col) * 64 + swz16);
#pragma unroll
        for (int u = 0; u < 4; ++u)
#pragma unroll
            for (int v = 0; v < 4; ++v)
                acc[u][v] = __builtin_amdgcn_mfma_f32_16x16x32_f16(fa[u], fb[v],
                                                                   acc[u][v], 0, 0, 0);
        if (kb + 1 < NS) {
            char* dA = SM + ((kb + 1) & 1) * 16384 + sOff;
            char* dB = SM + 32768 + ((kb + 1) & 1) * 8192 + sOff;
            if ((kb & 1) == 0) {
                *(f16x8*)dA = a10;
                *(f16x8*)(dA + 8192) = a11;
                *(f16x8*)dB = EXPB ? expb(b1, c10, c11) : b1;
                if (kb + 3 < NS) {
                    a10 = *(const f16x8*)(gA0 + (size_t)(kb + 3) * 64);
                    a11 = *(const f16x8*)(gA1 + (size_t)(kb + 3) * 64);
                    b1 = *(const f16x8*)(gB + (size_t)(kb + 3) * 64);
                    if (EXPB) {
                        c10 = *(const f32x4*)(gSp + (size_t)(kb + 3) * 32);
                        c11 = *(const f32x4*)(gSp + (size_t)(kb + 3) * 32 + 4);
                    }
                }
            } else {
                *(f16x8*)dA = a00;
                *(f16x8*)(dA + 8192) = a01;
                *(f16x8*)dB = EXPB ? expb(b0, c00, c01) : b0;
                if (kb + 3 < NS) {
                    a00 = *(const f16x8*)(gA0 + (size_t)(kb + 3) * 64);
                    a01 = *(const f16x8*)(gA1 + (size_t)(kb + 3) * 64);
                    b0 = *(const f16x8*)(gB + (size_t)(kb + 3) * 64);
                    if (EXPB) {
                        c00 = *(const f32x4*)(gSp + (size_t)(kb + 3) * 32);
                        c01 = *(const f32x4*)(gSp + (size_t)(kb + 3) * 32 + 4);
                    }
                }
            }
            WG_BARRIER();
        }
    }
}

// Transposed f16 epilogue (R4 verbatim): two m-half passes through Tt[128][136].
__device__ __forceinline__ void epilogue_tr(f32x4 (&acc)[4][4], char* SM, f16* dst0,
                                            int dstRow, int m0, int n0, int tid) {
    const int lane = tid & 63, wave = tid >> 6;
    const int col = lane & 15, quad = lane >> 4;
    const int wn = (wave >> 2) * 64;
    const int mh_w = (wave >> 1) & 1;
    const int wm_loc = (wave & 1) * 64;
    const int j = tid >> 2, seg = (tid & 3) * 32;
    WG_BARRIER();  // all frag reads of SM done before overwrite
    f16* Tt = (f16*)SM;
#pragma unroll
    for (int mh = 0; mh < 2; ++mh) {
        if (mh_w == mh) {
#pragma unroll
            for (int u = 0; u < 4; ++u)
#pragma unroll
                for (int v = 0; v < 4; ++v) {
                    f16x4 p;
#pragma unroll
                    for (int r = 0; r < 4; ++r) p[r] = (f16)acc[u][v][r];
                    *(f16x4*)&Tt[(wn + v * 16 + col) * 136 + wm_loc + u * 16 + quad * 4] = p;
                }
        }
        WG_BARRIER();
        f16* dst = dst0 + (size_t)(n0 + j) * dstRow + m0 + mh * 128 + seg;
#pragma unroll
        for (int c8 = 0; c8 < 32; c8 += 8)
            *(f16x8*)(dst + c8) = *(const f16x8*)&Tt[j * 136 + seg + c8];
        if (mh == 0) WG_BARRIER();
    }
}

// ---------------------------------------------------------------------------
// GEMM1: Xt[b][o][c] = (n1f[b] @ Wf^T)^T.  M=512, N=1024, K=1024. 256 blocks.
__global__ __launch_bounds__(512) void gemm1_nt_xt(const f16* __restrict__ A,
                                                   const f16* __restrict__ Bw,
                                                   f16* __restrict__ Xt) {
    const int K = 1024;
    const int id = blockIdx.x;
    const int xcd = id & 7, loc = id >> 3;         // loc 0..31
    const int b = xcd * 2 + (loc >> 4);
    const int m0 = ((loc >> 3) & 1) * 256;
    const int n0 = (loc & 7) * 128;
    A += (size_t)b * 512 * K;
    Xt += (size_t)b * 1024 * 512;
    __shared__ __attribute__((aligned(16))) char SM[49152];
    const int tid = threadIdx.x, lane = tid & 63, wave = tid >> 6;
    const int col = lane & 15, quad = lane >> 4;
    const int wm = (wave & 3) * 64, wn = (wave >> 2) * 64;
    const int srow = tid >> 2, sslot = tid & 3;
    const int sOff = srow * 64 + ((sslot ^ ((srow >> 1) & 3)) * 16);
    const int swz16 = (quad ^ ((col >> 1) & 3)) * 16;
    const char* gA0 = (const char*)A + (size_t)(m0 + srow) * K * 2 + sslot * 16;
    const char* gA1 = gA0 + (size_t)128 * K * 2;
    const char* gB = (const char*)Bw + (size_t)(n0 + srow) * K * 2 + sslot * 16;
    f32x4 acc[4][4] = {};
    gemm_core<32, false>(gA0, gA1, gB, nullptr, SM, sOff, wm, wn, col, swz16, acc);
    epilogue_tr(acc, SM, Xt, 512, m0, n0, tid);
}

// ---------------------------------------------------------------------------
// GEMM2: Et[b][h][o] (f16) = (Xt[b] @ n2t[b]^T)^T.  M=1024, N=1024, K=512.
// 512 blocks. Epilogue also emits per-block column (per-o) softmax partials
// from the f16-ROUNDED acc values (bit-consistent with stored Et).
__global__ __launch_bounds__(512) void gemm2_nt_et(const f16* __restrict__ A,
                                                   const f16* __restrict__ B,
                                                   f16* __restrict__ Et,
                                                   float* __restrict__ Pm,
                                                   float* __restrict__ Ps) {
    const int K = 512;
    const int id = blockIdx.x;
    const int xcd = id & 7, loc = id >> 3;         // loc 0..63
    const int b = xcd * 2 + (loc >> 5);
    const int m0 = ((loc >> 3) & 3) * 256;
    const int n0 = (loc & 7) * 128;
    A += (size_t)b * 1024 * K;
    B += (size_t)b * 1024 * K;
    Et += (size_t)b * 1024 * 1024;
    __shared__ __attribute__((aligned(16))) char SM[49152];
    const int tid = threadIdx.x, lane = tid & 63, wave = tid >> 6;
    const int col = lane & 15, quad = lane >> 4;
    const int wm = (wave & 3) * 64, wn = (wave >> 2) * 64;
    const int srow = tid >> 2, sslot = tid & 3;
    const int sOff = srow * 64 + ((sslot ^ ((srow >> 1) & 3)) * 16);
    const int swz16 = (quad ^ ((col >> 1) & 3)) * 16;
    const char* gA0 = (const char*)A + (size_t)(m0 + srow) * K * 2 + sslot * 16;
    const char* gA1 = gA0 + (size_t)128 * K * 2;
    const char* gB = (const char*)B + (size_t)(n0 + srow) * K * 2 + sslot * 16;
    f32x4 acc[4][4] = {};
    gemm_core<16, false>(gA0, gA1, gB, nullptr, SM, sOff, wm, wn, col, swz16, acc);

    // ---- fused column-softmax partials (log2 domain), registers + shfl only.
    // Values f16-rounded FIRST so stats match the Et that gemm3 re-reads.
    // Thread value (u,v,r): o = m0+wm+u*16+quad*4+r, h = n0+wn+v*16+col.
    {
        float pm[16], ps[16];
#pragma unroll
        for (int u = 0; u < 4; ++u)
#pragma unroll
            for (int r = 0; r < 4; ++r) {
                float w0 = (float)(f16)acc[u][0][r] * L2E;
                float w1 = (float)(f16)acc[u][1][r] * L2E;
                float w2 = (float)(f16)acc[u][2][r] * L2E;
                float w3 = (float)(f16)acc[u][3][r] * L2E;
                float m2 = fmaxf(fmaxf(w0, w1), fmaxf(w2, w3));
                float s = exp2f(w0 - m2) + exp2f(w1 - m2) +
                          exp2f(w2 - m2) + exp2f(w3 - m2);
                pm[u * 4 + r] = m2;
                ps[u * 4 + r] = s;
            }
#pragma unroll
        for (int d = 1; d < 16; d <<= 1)
#pragma unroll
            for (int i = 0; i < 16; ++i) {
                float om = __shfl_xor(pm[i], d, 64);
                float os = __shfl_xor(ps[i], d, 64);
                float nm = fmaxf(pm[i], om);
                ps[i] = ps[i] * exp2f(pm[i] - nm) + os * exp2f(om - nm);
                pm[i] = nm;
            }
        if (col == 0) {
            // partial p = nt*2 + nhalf; row block mt = m0>>8; o-local 0..255.
            const int part = ((b * 4 + (m0 >> 8)) * 8 + (n0 >> 7)) * 2 + (wave >> 2);
            float* bm = Pm + (size_t)part * 256;
            float* bs = Ps + (size_t)part * 256;
            const int wmq = (wave & 3) * 64 + quad * 4;
#pragma unroll
            for (int i = 0; i < 16; ++i) {
                const int ml = wmq + (i >> 2) * 16 + (i & 3);
                bm[ml] = pm[i];
                bs[ml] = ps[i];
            }
        }
    }

    epilogue_tr(acc, SM, Et, 1024, m0, n0, tid);
}

// ---------------------------------------------------------------------------
// GEMM3: out[b][c][j] (f32) = n2f[b](f16) @ At[b]^T, At[j][o] =
// exp2(Et[j][o]*log2e - Sc[b][o]) applied at B-staging (depth-2 covered).
// M=512, N=1024, K=1024. 256 blocks.
__global__ __launch_bounds__(512) void gemm3_nt_out(const f16* __restrict__ A,
                                                    const f16* __restrict__ Et,
                                                    const float* __restrict__ Sc,
                                                    float* __restrict__ C) {
    const int K = 1024;
    const int id = blockIdx.x;
    const int xcd = id & 7, loc = id >> 3;         // loc 0..31
    const int b = xcd * 2 + (loc >> 4);
    const int m0 = ((loc >> 3) & 1) * 256;
    const int n0 = (loc & 7) * 128;
    A += (size_t)b * 512 * K;
    Et += (size_t)b * 1024 * K;
    Sc += (size_t)b * 1024;
    C += (size_t)b * 512 * 1024;
    __shared__ __attribute__((aligned(16))) char SM[49152];
    const int tid = threadIdx.x, lane = tid & 63, wave = tid >> 6;
    const int col = lane & 15, quad = lane >> 4;
    const int wm = (wave & 3) * 64, wn = (wave >> 2) * 64;
    const int srow = tid >> 2, sslot = tid & 3;
    const int sOff = srow * 64 + ((sslot ^ ((srow >> 1) & 3)) * 16);
    const int swz16 = (quad ^ ((col >> 1) & 3)) * 16;
    const char* gA0 = (const char*)A + (size_t)(m0 + srow) * K * 2 + sslot * 16;
    const char* gA1 = gA0 + (size_t)128 * K * 2;
    const char* gB = (const char*)Et + (size_t)(n0 + srow) * K * 2 + sslot * 16;
    const float* gSp = Sc + sslot * 8;  // o-base of this thread's 8 staged elems
    f32x4 acc[4][4] = {};
    gemm_core<32, true>(gA0, gA1, gB, gSp, SM, sOff, wm, wn, col, swz16, acc);

#pragma unroll
    for (int u = 0; u < 4; ++u)
#pragma unroll
        for (int v = 0; v < 4; ++v)
#pragma unroll
            for (int r = 0; r < 4; ++r)
                C[(size_t)(m0 + wm + u * 16 + quad * 4 + r) * 1024 + n0 + wn + v * 16 + col] =
                    acc[u][v][r];
}

// ---------------------------------------------------------------------------
extern "C" void kernel_launch(void* const* d_in, const int* in_sizes, int n_in,
                              void* d_out, int out_size, void* d_ws, size_t ws_size,
                              hipStream_t stream) {
    const float* n1 = (const float*)d_in[0];
    const float* n2 = (const float*)d_in[1];
    const float* Wc = (const float*)d_in[2];
    float* out = (float*)d_out;
    char* ws = (char*)d_ws;

    f16* n2t = (f16*)(ws);                   // [0,16M)   prep -> gemm2
    f16* Xt  = (f16*)(ws + (16u << 20));     // [16,32M)  gemm1 -> gemm2
    f16* Wf  = (f16*)(ws + (32u << 20));     // [32,34M)  prep -> gemm1 (dead before Et)
    f16* Et  = (f16*)(ws + (32u << 20));     // [32,64M)  gemm2 -> gemm3
    f16* n1f = (f16*)(ws + (64u << 20));     // [64,80M)  prep -> gemm1 (dead after)
    f16* n2f = (f16*)(ws + (80u << 20));     // [80,96M)  prep -> gemm3
    float* Pm = (float*)(ws + (64u << 20));            // 1 MiB, over dead n1f
    float* Ps = (float*)(ws + (65u << 20));            // 1 MiB
    float* Sc = (float*)(ws + (66u << 20));            // 64 KiB (log2 units)

    prep<<<6656, dim3(256), 0, stream>>>(n1, Wc, n2, n1f, Wf, n2f, n2t);
    gemm1_nt_xt<<<256, dim3(512), 0, stream>>>(n1f, Wf, Xt);
    gemm2_nt_et<<<512, dim3(512), 0, stream>>>(Xt, n2t, Et, Pm, Ps);
    stats_combine<<<64, dim3(256), 0, stream>>>(Pm, Ps, Sc);
    gemm3_nt_out<<<256, dim3(512), 0, stream>>>(n2f, Et, Sc, out);
}

// Round 9
// 202.735 us; speedup vs baseline: 1.1543x; 1.0680x over previous
//
#include <hip/hip_runtime.h>
#include <math.h>

// B=16, C=512, HW=1024.  Chain (per batch):
//   X  (C x HW)  = n1 @ W_c^T
//   E  (HW x HW) = X^T @ n2
//   A  = row-softmax(E)
//   out(C x HW)  = n2 @ A
//
// Round 16: register-lean stats fusion (fix round-15's occupancy collapse).
//  - gemm2's shfl-based stats (32 live VGPRs -> 1 block/CU, 74us) replaced
//    by a Tt-based reduction: the transposed epilogue already materializes
//    the f16-rounded Et tile in LDS (o = columns); each thread reduces one
//    o-column over a 32-row strip (rotated reads), 2-step shfl combine,
//    8 partials per (b,o). ~4 live registers instead of 32.
//  - Everything else = the R4-verbatim composition: 512-thread GEMM core
//    (BM=256 BN=128 BK=32, 8 waves, 64x64 wave tiles, both-sides XOR
//    swizzle, depth-2 reg prefetch), exp fused in gemm3 B-staging.
//  - Pipeline: prep -> gemm1 -> gemm2(+stats) -> stats_combine -> gemm3.
//
// Workspace (96 MiB, lifetime-aliased):
//   [0,16M):   n2t  f16 (prep -> gemm2)
//   [16,32M):  Xt   f16 (gemm1 -> gemm2)
//   [32,34M):  Wf   f16 (prep -> gemm1; overlaid by Et)
//   [32,64M):  Et   f16 (gemm2 -> gemm3)
//   [64,80M):  n1f  f16 (prep -> gemm1); Pm/Ps/Sc overlay afterwards
//   [80,96M):  n2f  f16 (prep -> gemm3)

typedef _Float16 f16;
typedef _Float16 f16x8 __attribute__((ext_vector_type(8)));
typedef _Float16 f16x4 __attribute__((ext_vector_type(4)));
typedef float f32x4 __attribute__((ext_vector_type(4)));

#define L2E 1.442695040888963f

// Barrier with LDS-drain only (no vmcnt drain): prefetch survives it.
#define WG_BARRIER() asm volatile("s_waitcnt lgkmcnt(0)\ns_barrier" ::: "memory")

// ---------------------------------------------------------------------------
// Fused pre-pass. blockIdx.x:
//   [0,4096):    n1 -> n1f     [4096,4608): Wc -> Wf
//   [4608,6656): n2 -> n2f (natural) + n2t (transposed)
__global__ __launch_bounds__(256) void prep(const float* __restrict__ n1,
                                            const float* __restrict__ Wc,
                                            const float* __restrict__ n2,
                                            f16* __restrict__ n1f, f16* __restrict__ Wf,
                                            f16* __restrict__ n2f, f16* __restrict__ n2t) {
    const int bid = blockIdx.x, tid = threadIdx.x;
    if (bid < 4608) {
        const float* s = (bid < 4096) ? n1 : Wc;
        f16* d = (bid < 4096) ? n1f : Wf;
        const size_t i = ((size_t)(bid < 4096 ? bid : bid - 4096) * 256 + tid) * 8;
        f32x4 a = *(const f32x4*)(s + i);
        f32x4 b = *(const f32x4*)(s + i + 4);
        f16x8 o;
        o[0] = (f16)a[0]; o[1] = (f16)a[1]; o[2] = (f16)a[2]; o[3] = (f16)a[3];
        o[4] = (f16)b[0]; o[5] = (f16)b[1]; o[6] = (f16)b[2]; o[7] = (f16)b[3];
        *(f16x8*)(d + i) = o;
        return;
    }
    const int id = bid - 4608;
    const int b = id >> 7;
    const int ry = (id & 127) >> 4;
    const int cx = id & 15;
    const float* S = n2 + (size_t)b * 512 * 1024;
    f16* Dn = n2f + (size_t)b * 512 * 1024;
    f16* Dt = n2t + (size_t)b * 1024 * 512;
    __shared__ f16 Ts[64 * 72];
    const int r0 = ry * 64, c0 = cx * 64;
    const int rr = tid >> 3, cc8 = (tid & 7) * 8;
#pragma unroll
    for (int h = 0; h < 2; ++h) {
        const int row = r0 + rr + 32 * h;
        const float* s = S + (size_t)row * 1024 + c0 + cc8;
        f32x4 a = *(const f32x4*)s, bq = *(const f32x4*)(s + 4);
        f16x8 o;
        o[0] = (f16)a[0]; o[1] = (f16)a[1]; o[2] = (f16)a[2]; o[3] = (f16)a[3];
        o[4] = (f16)bq[0]; o[5] = (f16)bq[1]; o[6] = (f16)bq[2]; o[7] = (f16)bq[3];
        *(f16x8*)&Ts[(rr + 32 * h) * 72 + cc8] = o;
        *(f16x8*)(Dn + (size_t)row * 1024 + c0 + cc8) = o;
    }
    __syncthreads();
    const int j = tid >> 2, k16 = (tid & 3) * 16;
    f16* d = Dt + (size_t)(c0 + j) * 512 + r0 + k16;
    f16x8 o0, o1;
#pragma unroll
    for (int i = 0; i < 8; ++i) {
        o0[i] = Ts[(k16 + i) * 72 + j];
        o1[i] = Ts[(k16 + 8 + i) * 72 + j];
    }
    *(f16x8*)d = o0;
    *(f16x8*)(d + 8) = o1;
}

// ---------------------------------------------------------------------------
// stats_combine: per (b,o) fold 8 partials (log2 domain) ->
//   Sc[b][o] = log2(sum_h e^{E[o][h]}), log2 units.
// Partial layout: Pm[((b*4 + mt)*8 + nt)*256 + ml], mt = o>>8, ml = o&255.
__global__ __launch_bounds__(256) void stats_combine(const float* __restrict__ Pm,
                                                     const float* __restrict__ Ps,
                                                     float* __restrict__ Sc) {
    const int g = blockIdx.x * 256 + threadIdx.x;  // 16 * 1024
    const int b = g >> 10, o = g & 1023;
    const int mt = o >> 8, ml = o & 255;
    const float* pm = Pm + ((size_t)(b * 4 + mt) * 8) * 256 + ml;
    const float* ps = Ps + ((size_t)(b * 4 + mt) * 8) * 256 + ml;
    float M = -3.0e38f;
#pragma unroll
    for (int p = 0; p < 8; ++p) M = fmaxf(M, pm[p * 256]);
    float S = 0.f;
#pragma unroll
    for (int p = 0; p < 8; ++p) S += ps[p * 256] * exp2f(pm[p * 256] - M);
    Sc[g] = M + __log2f(S);
}

// ---------------------------------------------------------------------------
// exp-scale of a staged B vector: At = exp2(Et*log2e - Sc)
__device__ __forceinline__ f16x8 expb(f16x8 b, f32x4 cl, f32x4 ch) {
    f16x8 t;
#pragma unroll
    for (int i = 0; i < 4; ++i) t[i] = (f16)exp2f(fmaf((float)b[i], L2E, -cl[i]));
#pragma unroll
    for (int i = 0; i < 4; ++i) t[4 + i] = (f16)exp2f(fmaf((float)b[4 + i], L2E, -ch[i]));
    return t;
}

// ---------------------------------------------------------------------------
// Shared K-loop core (R4 verbatim). BM=256, BN=128, BK=32, 512 threads,
// 8 waves (4m x 2n), wave tile 64x64: fa[4] x fb[4] -> 16 MFMA per
// 8 ds_read_b128. LDS: A0 @0 (16K), A1 @16384, B0 @32768 (8K), B1 @40960.
// Row = 64 B. Swizzle: 16B slot s of row r lives at s ^ ((r>>1)&3);
// applied on both stage-write (sOff) and fragment-read (swz16).
// Depth-2 global->reg prefetch.
template <int NS, bool EXPB>
__device__ __forceinline__ void gemm_core(const char* gA0, const char* gA1,
                                          const char* gB, const float* gSp,
                                          char* SM, int sOff, int wm, int wn,
                                          int col, int swz16, f32x4 (&acc)[4][4]) {
    f16x8 a00 = *(const f16x8*)gA0, a01 = *(const f16x8*)gA1;
    f16x8 b0 = *(const f16x8*)gB;
    f32x4 c00, c01, c10, c11;
    if (EXPB) { c00 = *(const f32x4*)gSp; c01 = *(const f32x4*)(gSp + 4); }
    {
        char* dA = SM + sOff;
        *(f16x8*)dA = a00;
        *(f16x8*)(dA + 8192) = a01;
        char* dB = SM + 32768 + sOff;
        *(f16x8*)dB = EXPB ? expb(b0, c00, c01) : b0;
    }
    f16x8 a10 = *(const f16x8*)(gA0 + 64), a11 = *(const f16x8*)(gA1 + 64);
    f16x8 b1 = *(const f16x8*)(gB + 64);
    if (EXPB) { c10 = *(const f32x4*)(gSp + 32); c11 = *(const f32x4*)(gSp + 36); }
    a00 = *(const f16x8*)(gA0 + 128); a01 = *(const f16x8*)(gA1 + 128);
    b0 = *(const f16x8*)(gB + 128);
    if (EXPB) { c00 = *(const f32x4*)(gSp + 64); c01 = *(const f32x4*)(gSp + 68); }
    WG_BARRIER();
#pragma unroll
    for (int kb = 0; kb < NS; ++kb) {
        const char* Ac = SM + (kb & 1) * 16384;
        const char* Bc = SM + 32768 + (kb & 1) * 8192;
        f16x8 fa[4], fb[4];
#pragma unroll
        for (int u = 0; u < 4; ++u)
            fa[u] = *(const f16x8*)(Ac + (wm + u * 16 + col) * 64 + swz16);
#pragma unroll
        for (int v = 0; v < 4; ++v)
            fb[v] = *(const f16x8*)(Bc + (wn + v * 16 + col) * 64 + swz16);
#pragma unroll
        for (int u = 0; u < 4; ++u)
#pragma unroll
            for (int v = 0; v < 4; ++v)
                acc[u][v] = __builtin_amdgcn_mfma_f32_16x16x32_f16(fa[u], fb[v],
                                                                   acc[u][v], 0, 0, 0);
        if (kb + 1 < NS) {
            char* dA = SM + ((kb + 1) & 1) * 16384 + sOff;
            char* dB = SM + 32768 + ((kb + 1) & 1) * 8192 + sOff;
            if ((kb & 1) == 0) {
                *(f16x8*)dA = a10;
                *(f16x8*)(dA + 8192) = a11;
                *(f16x8*)dB = EXPB ? expb(b1, c10, c11) : b1;
                if (kb + 3 < NS) {
                    a10 = *(const f16x8*)(gA0 + (size_t)(kb + 3) * 64);
                    a11 = *(const f16x8*)(gA1 + (size_t)(kb + 3) * 64);
                    b1 = *(const f16x8*)(gB + (size_t)(kb + 3) * 64);
                    if (EXPB) {
                        c10 = *(const f32x4*)(gSp + (size_t)(kb + 3) * 32);
                        c11 = *(const f32x4*)(gSp + (size_t)(kb + 3) * 32 + 4);
                    }
                }
            } else {
                *(f16x8*)dA = a00;
                *(f16x8*)(dA + 8192) = a01;
                *(f16x8*)dB = EXPB ? expb(b0, c00, c01) : b0;
                if (kb + 3 < NS) {
                    a00 = *(const f16x8*)(gA0 + (size_t)(kb + 3) * 64);
                    a01 = *(const f16x8*)(gA1 + (size_t)(kb + 3) * 64);
                    b0 = *(const f16x8*)(gB + (size_t)(kb + 3) * 64);
                    if (EXPB) {
                        c00 = *(const f32x4*)(gSp + (size_t)(kb + 3) * 32);
                        c01 = *(const f32x4*)(gSp + (size_t)(kb + 3) * 32 + 4);
                    }
                }
            }
            WG_BARRIER();
        }
    }
}

// Transposed f16 epilogue (R4 verbatim): two m-half passes through Tt[128][136].
__device__ __forceinline__ void epilogue_tr(f32x4 (&acc)[4][4], char* SM, f16* dst0,
                                            int dstRow, int m0, int n0, int tid) {
    const int lane = tid & 63, wave = tid >> 6;
    const int col = lane & 15, quad = lane >> 4;
    const int wn = (wave >> 2) * 64;
    const int mh_w = (wave >> 1) & 1;
    const int wm_loc = (wave & 1) * 64;
    const int j = tid >> 2, seg = (tid & 3) * 32;
    WG_BARRIER();  // all frag reads of SM done before overwrite
    f16* Tt = (f16*)SM;
#pragma unroll
    for (int mh = 0; mh < 2; ++mh) {
        if (mh_w == mh) {
#pragma unroll
            for (int u = 0; u < 4; ++u)
#pragma unroll
                for (int v = 0; v < 4; ++v) {
                    f16x4 p;
#pragma unroll
                    for (int r = 0; r < 4; ++r) p[r] = (f16)acc[u][v][r];
                    *(f16x4*)&Tt[(wn + v * 16 + col) * 136 + wm_loc + u * 16 + quad * 4] = p;
                }
        }
        WG_BARRIER();
        f16* dst = dst0 + (size_t)(n0 + j) * dstRow + m0 + mh * 128 + seg;
#pragma unroll
        for (int c8 = 0; c8 < 32; c8 += 8)
            *(f16x8*)(dst + c8) = *(const f16x8*)&Tt[j * 136 + seg + c8];
        if (mh == 0) WG_BARRIER();
    }
}

// ---------------------------------------------------------------------------
// GEMM1: Xt[b][o][c] = (n1f[b] @ Wf^T)^T.  M=512, N=1024, K=1024. 256 blocks.
__global__ __launch_bounds__(512) void gemm1_nt_xt(const f16* __restrict__ A,
                                                   const f16* __restrict__ Bw,
                                                   f16* __restrict__ Xt) {
    const int K = 1024;
    const int id = blockIdx.x;
    const int xcd = id & 7, loc = id >> 3;         // loc 0..31
    const int b = xcd * 2 + (loc >> 4);
    const int m0 = ((loc >> 3) & 1) * 256;
    const int n0 = (loc & 7) * 128;
    A += (size_t)b * 512 * K;
    Xt += (size_t)b * 1024 * 512;
    __shared__ __attribute__((aligned(16))) char SM[49152];
    const int tid = threadIdx.x, lane = tid & 63, wave = tid >> 6;
    const int col = lane & 15, quad = lane >> 4;
    const int wm = (wave & 3) * 64, wn = (wave >> 2) * 64;
    const int srow = tid >> 2, sslot = tid & 3;
    const int sOff = srow * 64 + ((sslot ^ ((srow >> 1) & 3)) * 16);
    const int swz16 = (quad ^ ((col >> 1) & 3)) * 16;
    const char* gA0 = (const char*)A + (size_t)(m0 + srow) * K * 2 + sslot * 16;
    const char* gA1 = gA0 + (size_t)128 * K * 2;
    const char* gB = (const char*)Bw + (size_t)(n0 + srow) * K * 2 + sslot * 16;
    f32x4 acc[4][4] = {};
    gemm_core<32, false>(gA0, gA1, gB, nullptr, SM, sOff, wm, wn, col, swz16, acc);
    epilogue_tr(acc, SM, Xt, 512, m0, n0, tid);
}

// ---------------------------------------------------------------------------
// GEMM2: Et[b][h][o] (f16) = (Xt[b] @ n2t[b]^T)^T.  M=1024, N=1024, K=512.
// 512 blocks. Epilogue fuses column-softmax partials computed FROM Tt (the
// f16-rounded tile in LDS, bit-consistent with stored Et). Register-lean:
// each thread reduces one o-column over a 32-row strip, 2-step shfl combine.
__global__ __launch_bounds__(512) void gemm2_nt_et(const f16* __restrict__ A,
                                                   const f16* __restrict__ B,
                                                   f16* __restrict__ Et,
                                                   float* __restrict__ Pm,
                                                   float* __restrict__ Ps) {
    const int K = 512;
    const int id = blockIdx.x;
    const int xcd = id & 7, loc = id >> 3;         // loc 0..63
    const int b = xcd * 2 + (loc >> 5);
    const int m0 = ((loc >> 3) & 3) * 256;
    const int n0 = (loc & 7) * 128;
    A += (size_t)b * 1024 * K;
    B += (size_t)b * 1024 * K;
    Et += (size_t)b * 1024 * 1024;
    __shared__ __attribute__((aligned(16))) char SM[49152];
    const int tid = threadIdx.x, lane = tid & 63, wave = tid >> 6;
    const int col = lane & 15, quad = lane >> 4;
    const int wm = (wave & 3) * 64, wn = (wave >> 2) * 64;
    const int srow = tid >> 2, sslot = tid & 3;
    const int sOff = srow * 64 + ((sslot ^ ((srow >> 1) & 3)) * 16);
    const int swz16 = (quad ^ ((col >> 1) & 3)) * 16;
    const char* gA0 = (const char*)A + (size_t)(m0 + srow) * K * 2 + sslot * 16;
    const char* gA1 = gA0 + (size_t)128 * K * 2;
    const char* gB = (const char*)B + (size_t)(n0 + srow) * K * 2 + sslot * 16;
    f32x4 acc[4][4] = {};
    gemm_core<16, false>(gA0, gA1, gB, nullptr, SM, sOff, wm, wn, col, swz16, acc);

    // ---- transposed epilogue + fused column-softmax stats from Tt.
    {
        const int wn_e = (wave >> 2) * 64;
        const int mh_w = (wave >> 1) & 1;
        const int wm_loc = (wave & 1) * 64;
        const int j = tid >> 2, seg = (tid & 3) * 32;
        const int scol = tid >> 2, srq = tid & 3;   // o-column, row-quarter
        WG_BARRIER();  // all frag reads of SM done before overwrite
        f16* Tt = (f16*)SM;
#pragma unroll
        for (int mh = 0; mh < 2; ++mh) {
            if (mh_w == mh) {
#pragma unroll
                for (int u = 0; u < 4; ++u)
#pragma unroll
                    for (int v = 0; v < 4; ++v) {
                        f16x4 p;
#pragma unroll
                        for (int r = 0; r < 4; ++r) p[r] = (f16)acc[u][v][r];
                        *(f16x4*)&Tt[(wn_e + v * 16 + col) * 136 + wm_loc + u * 16 + quad * 4] = p;
                    }
            }
            WG_BARRIER();
            // coalesced Et rows
            f16* dst = Et + (size_t)(n0 + j) * 1024 + m0 + mh * 128 + seg;
#pragma unroll
            for (int c8 = 0; c8 < 32; c8 += 8)
                *(f16x8*)(dst + c8) = *(const f16x8*)&Tt[j * 136 + seg + c8];
            // stats: o = m0 + mh*128 + scol; rows srq*32..+32 (rotated reads).
            float mx = -3.0e38f;
#pragma unroll
            for (int n = 0; n < 32; ++n) {
                const int row = srq * 32 + ((n + scol) & 31);
                mx = fmaxf(mx, (float)Tt[row * 136 + scol]);
            }
            const float mxl = mx * L2E;
            float s = 0.f;
#pragma unroll
            for (int n = 0; n < 32; ++n) {
                const int row = srq * 32 + ((n + scol) & 31);
                s += exp2f(fmaf((float)Tt[row * 136 + scol], L2E, -mxl));
            }
            float pmv = mxl, psv = s;
#pragma unroll
            for (int d = 1; d < 4; d <<= 1) {
                float om = __shfl_xor(pmv, d, 64);
                float os = __shfl_xor(psv, d, 64);
                float nm = fmaxf(pmv, om);
                psv = psv * exp2f(pmv - nm) + os * exp2f(om - nm);
                pmv = nm;
            }
            if (srq == 0) {
                const int part = (b * 4 + (m0 >> 8)) * 8 + (n0 >> 7);
                const int ml = mh * 128 + scol;
                Pm[(size_t)part * 256 + ml] = pmv;
                Ps[(size_t)part * 256 + ml] = psv;
            }
            if (mh == 0) WG_BARRIER();
        }
    }
}

// ---------------------------------------------------------------------------
// GEMM3: out[b][c][j] (f32) = n2f[b](f16) @ At[b]^T, At[j][o] =
// exp2(Et[j][o]*log2e - Sc[b][o]) applied at B-staging (depth-2 covered).
// M=512, N=1024, K=1024. 256 blocks.
__global__ __launch_bounds__(512) void gemm3_nt_out(const f16* __restrict__ A,
                                                    const f16* __restrict__ Et,
                                                    const float* __restrict__ Sc,
                                                    float* __restrict__ C) {
    const int K = 1024;
    const int id = blockIdx.x;
    const int xcd = id & 7, loc = id >> 3;         // loc 0..31
    const int b = xcd * 2 + (loc >> 4);
    const int m0 = ((loc >> 3) & 1) * 256;
    const int n0 = (loc & 7) * 128;
    A += (size_t)b * 512 * K;
    Et += (size_t)b * 1024 * K;
    Sc += (size_t)b * 1024;
    C += (size_t)b * 512 * 1024;
    __shared__ __attribute__((aligned(16))) char SM[49152];
    const int tid = threadIdx.x, lane = tid & 63, wave = tid >> 6;
    const int col = lane & 15, quad = lane >> 4;
    const int wm = (wave & 3) * 64, wn = (wave >> 2) * 64;
    const int srow = tid >> 2, sslot = tid & 3;
    const int sOff = srow * 64 + ((sslot ^ ((srow >> 1) & 3)) * 16);
    const int swz16 = (quad ^ ((col >> 1) & 3)) * 16;
    const char* gA0 = (const char*)A + (size_t)(m0 + srow) * K * 2 + sslot * 16;
    const char* gA1 = gA0 + (size_t)128 * K * 2;
    const char* gB = (const char*)Et + (size_t)(n0 + srow) * K * 2 + sslot * 16;
    const float* gSp = Sc + sslot * 8;  // o-base of this thread's 8 staged elems
    f32x4 acc[4][4] = {};
    gemm_core<32, true>(gA0, gA1, gB, gSp, SM, sOff, wm, wn, col, swz16, acc);

#pragma unroll
    for (int u = 0; u < 4; ++u)
#pragma unroll
        for (int v = 0; v < 4; ++v)
#pragma unroll
            for (int r = 0; r < 4; ++r)
                C[(size_t)(m0 + wm + u * 16 + quad * 4 + r) * 1024 + n0 + wn + v * 16 + col] =
                    acc[u][v][r];
}

// ---------------------------------------------------------------------------
extern "C" void kernel_launch(void* const* d_in, const int* in_sizes, int n_in,
                              void* d_out, int out_size, void* d_ws, size_t ws_size,
                              hipStream_t stream) {
    const float* n1 = (const float*)d_in[0];
    const float* n2 = (const float*)d_in[1];
    const float* Wc = (const float*)d_in[2];
    float* out = (float*)d_out;
    char* ws = (char*)d_ws;

    f16* n2t = (f16*)(ws);                   // [0,16M)   prep -> gemm2
    f16* Xt  = (f16*)(ws + (16u << 20));     // [16,32M)  gemm1 -> gemm2
    f16* Wf  = (f16*)(ws + (32u << 20));     // [32,34M)  prep -> gemm1 (dead before Et)
    f16* Et  = (f16*)(ws + (32u << 20));     // [32,64M)  gemm2 -> gemm3
    f16* n1f = (f16*)(ws + (64u << 20));     // [64,80M)  prep -> gemm1 (dead after)
    f16* n2f = (f16*)(ws + (80u << 20));     // [80,96M)  prep -> gemm3
    float* Pm = (float*)(ws + (64u << 20));            // 512 KiB, over dead n1f
    float* Ps = (float*)(ws + (65u << 20));            // 512 KiB
    float* Sc = (float*)(ws + (66u << 20));            // 64 KiB (log2 units)

    prep<<<6656, dim3(256), 0, stream>>>(n1, Wc, n2, n1f, Wf, n2f, n2t);
    gemm1_nt_xt<<<256, dim3(512), 0, stream>>>(n1f, Wf, Xt);
    gemm2_nt_et<<<512, dim3(512), 0, stream>>>(Xt, n2t, Et, Pm, Ps);
    stats_combine<<<64, dim3(256), 0, stream>>>(Pm, Ps, Sc);
    gemm3_nt_out<<<256, dim3(512), 0, stream>>>(n2f, Et, Sc, out);
}